// Round 1
// baseline (596.823 us; speedup 1.0000x reference)
//
#include <hip/hip_runtime.h>

#define BTOT 131072
#define TSEQ 15
#define BM   32

typedef __attribute__((ext_vector_type(8))) short bf16x8;
typedef __attribute__((ext_vector_type(4))) float f32x4;

__device__ __forceinline__ short f2bf(float f){
  union{float f; unsigned u;} v; v.f=f;
  unsigned r = v.u + 0x7FFFu + ((v.u>>16)&1u);
  return (short)(r>>16);
}

__device__ __forceinline__ float fast_sigmoid(float x){
  float e = __expf(-x);
  return __builtin_amdgcn_rcpf(1.f + e);
}
__device__ __forceinline__ float fast_tanh(float x){
  float e = __expf(2.f*x);
  return 1.f - 2.f*__builtin_amdgcn_rcpf(e + 1.f);
}

// ---------------- kernel 1: per-timestep batch statistics ----------------
__global__ void bn_stats(const float* __restrict__ x, float* __restrict__ sums){
  float s[TSEQ], s2[TSEQ];
  #pragma unroll
  for (int t=0;t<TSEQ;t++){ s[t]=0.f; s2[t]=0.f; }
  for (int b = blockIdx.x*blockDim.x + threadIdx.x; b < BTOT; b += gridDim.x*blockDim.x){
    const float* row = x + b*TSEQ;
    #pragma unroll
    for (int t=0;t<TSEQ;t++){ float v = row[t]; s[t]+=v; s2[t]+=v*v; }
  }
  #pragma unroll
  for (int t=0;t<TSEQ;t++){
    #pragma unroll
    for (int off=32; off>0; off>>=1){
      s[t]  += __shfl_down(s[t],  off, 64);
      s2[t] += __shfl_down(s2[t], off, 64);
    }
  }
  if ((threadIdx.x & 63) == 0){
    #pragma unroll
    for (int t=0;t<TSEQ;t++){
      atomicAdd(&sums[t],      s[t]);
      atomicAdd(&sums[TSEQ+t], s2[t]);
    }
  }
}

// ---------------- kernel 2: fused BN + 2-layer LSTM + FC ----------------
__global__ __launch_bounds__(256, 2) void lstm_fused(
    const float* __restrict__ x,
    const float* __restrict__ gamma, const float* __restrict__ beta,
    const float* __restrict__ Wih0,  const float* __restrict__ Whh0,
    const float* __restrict__ bih0,  const float* __restrict__ bhh0,
    const float* __restrict__ Wih1,  const float* __restrict__ Whh1,
    const float* __restrict__ bih1,  const float* __restrict__ bhh1,
    const float* __restrict__ Wfc,   const float* __restrict__ bfc,
    const float* __restrict__ sums,  float* __restrict__ out)
{
  __shared__ alignas(16) short h0s[BM*64];   // bf16 bits, row stride 128B, XOR-swizzled
  __shared__ alignas(16) short h1s[BM*64];
  __shared__ float xns[BM][16];              // normalized x tile (padded)
  __shared__ float scs[TSEQ], shs[TSEQ];

  const int tid  = threadIdx.x;
  const int w    = tid >> 6;        // wave id 0..3 -> owns h columns [w*16, w*16+16)
  const int lane = tid & 63;
  const int l15  = lane & 15;
  const int lg   = lane >> 4;
  const int rbase = blockIdx.x * BM;

  if (tid < TSEQ){
    const float inv = 1.f/(float)BTOT;
    float mean = sums[tid]*inv;
    float var  = sums[TSEQ+tid]*inv - mean*mean;
    float sc = gamma[tid] * rsqrtf(var + 1e-5f);
    scs[tid] = sc;
    shs[tid] = beta[tid] - mean*sc;
  }
  #pragma unroll
  for (int i=0;i<8;i++){ h0s[tid + i*256] = 0; h1s[tid + i*256] = 0; }
  __syncthreads();
  for (int i = tid; i < BM*TSEQ; i += 256){
    int r = i/TSEQ, t = i - r*TSEQ;
    xns[r][t] = x[(rbase+r)*TSEQ + t] * scs[t] + shs[t];
  }

  // ---- per-lane constants & weight B-fragments (registers, bf16) ----
  // B-frag layout for mfma_f32_16x16x32_bf16: col = lane&15, k = (lane>>4)*8 + e
  float wx0[4], bs0[4], bs1[4];
  bf16x8 wB0[2][4], wB1[4][4], wFC[2];
  #pragma unroll
  for (int n=0;n<4;n++){
    int g = n*64 + w*16 + l15;          // gate column (i/f/g/o block n)
    wx0[n] = Wih0[g];
    bs0[n] = bih0[g] + bhh0[g];
    bs1[n] = bih1[g] + bhh1[g];
    #pragma unroll
    for (int kk=0;kk<2;kk++){
      const float* p = Whh0 + g*64 + kk*32 + lg*8;
      #pragma unroll
      for (int e=0;e<8;e++) wB0[kk][n][e] = f2bf(p[e]);
    }
    #pragma unroll
    for (int kk=0;kk<4;kk++){           // combined K=128: [W_ih1 | W_hh1]
      const float* bsrc = (kk<2) ? Wih1 : Whh1;
      const float* p = bsrc + g*64 + (kk&1)*32 + lg*8;
      #pragma unroll
      for (int e=0;e<8;e++) wB1[kk][n][e] = f2bf(p[e]);
    }
  }
  float fcb;
  {
    int o = w*16 + l15;
    fcb = bfc[o];
    #pragma unroll
    for (int kk=0;kk<2;kk++){
      const float* p = Wfc + o*64 + kk*32 + lg*8;
      #pragma unroll
      for (int e=0;e<8;e++) wFC[kk][e] = f2bf(p[e]);
    }
  }

  // cell state in MFMA C-layout: row = m*16 + lg*4 + r, col = w*16 + l15
  f32x4 c0[2], c1[2];
  #pragma unroll
  for (int m=0;m<2;m++){
    c0[m] = (f32x4){0.f,0.f,0.f,0.f};
    c1[m] = (f32x4){0.f,0.f,0.f,0.f};
  }

  __syncthreads();

  #pragma unroll 1
  for (int t=0; t<TSEQ; t++){
    f32x4 acc[2][4];
    // ----- layer 0: gates = bias + xn*W_ih0 (rank-1, I=1) + h0 @ Whh0^T -----
    #pragma unroll
    for (int m=0;m<2;m++){
      #pragma unroll
      for (int r=0;r<4;r++){
        float xv = xns[m*16 + lg*4 + r][t];
        #pragma unroll
        for (int n=0;n<4;n++) acc[m][n][r] = __builtin_fmaf(xv, wx0[n], bs0[n]);
      }
    }
    #pragma unroll
    for (int kk=0;kk<2;kk++){
      #pragma unroll
      for (int m=0;m<2;m++){
        int row = m*16 + l15;
        int off = (row*128 + kk*64 + lg*16) ^ ((row&7)<<4);
        bf16x8 a = *(const bf16x8*)((const char*)h0s + off);
        #pragma unroll
        for (int n=0;n<4;n++)
          acc[m][n] = __builtin_amdgcn_mfma_f32_16x16x32_bf16(a, wB0[kk][n], acc[m][n], 0,0,0);
      }
    }
    float h0n[2][4];
    #pragma unroll
    for (int m=0;m<2;m++){
      #pragma unroll
      for (int r=0;r<4;r++){
        float iv = fast_sigmoid(acc[m][0][r]);
        float fv = fast_sigmoid(acc[m][1][r]);
        float gv = fast_tanh   (acc[m][2][r]);
        float ov = fast_sigmoid(acc[m][3][r]);
        float c  = __builtin_fmaf(fv, c0[m][r], iv*gv);
        c0[m][r] = c;
        h0n[m][r] = ov * fast_tanh(c);
      }
    }
    __syncthreads();                    // B1: all waves done reading h0(t-1)
    #pragma unroll
    for (int m=0;m<2;m++){
      #pragma unroll
      for (int r=0;r<4;r++){
        int row = m*16 + lg*4 + r;
        int off = (row*128 + (w*16 + l15)*2) ^ ((row&7)<<4);
        *(short*)((char*)h0s + off) = f2bf(h0n[m][r]);
      }
    }
    __syncthreads();                    // B2: h0(t) visible

    // ----- layer 1: gates = bias + [h0(t)|h1(t-1)] @ [Wih1|Whh1]^T -----
    #pragma unroll
    for (int m=0;m<2;m++)
      #pragma unroll
      for (int n=0;n<4;n++)
        #pragma unroll
        for (int r=0;r<4;r++)
          acc[m][n][r] = bs1[n];
    #pragma unroll
    for (int kk=0;kk<4;kk++){
      const short* asrc = (kk<2) ? h0s : h1s;
      #pragma unroll
      for (int m=0;m<2;m++){
        int row = m*16 + l15;
        int off = (row*128 + (kk&1)*64 + lg*16) ^ ((row&7)<<4);
        bf16x8 a = *(const bf16x8*)((const char*)asrc + off);
        #pragma unroll
        for (int n=0;n<4;n++)
          acc[m][n] = __builtin_amdgcn_mfma_f32_16x16x32_bf16(a, wB1[kk][n], acc[m][n], 0,0,0);
      }
    }
    float h1n[2][4];
    #pragma unroll
    for (int m=0;m<2;m++){
      #pragma unroll
      for (int r=0;r<4;r++){
        float iv = fast_sigmoid(acc[m][0][r]);
        float fv = fast_sigmoid(acc[m][1][r]);
        float gv = fast_tanh   (acc[m][2][r]);
        float ov = fast_sigmoid(acc[m][3][r]);
        float c  = __builtin_fmaf(fv, c1[m][r], iv*gv);
        c1[m][r] = c;
        h1n[m][r] = ov * fast_tanh(c);
      }
    }
    __syncthreads();                    // B3: all waves done reading h1(t-1)
    #pragma unroll
    for (int m=0;m<2;m++){
      #pragma unroll
      for (int r=0;r<4;r++){
        int row = m*16 + lg*4 + r;
        int off = (row*128 + (w*16 + l15)*2) ^ ((row&7)<<4);
        *(short*)((char*)h1s + off) = f2bf(h1n[m][r]);
      }
    }
  }
  __syncthreads();                      // h1(T-1) visible for FC

  // ----- FC: out = relu(h1 @ Wfc^T + bfc) -----
  f32x4 accF[2];
  #pragma unroll
  for (int m=0;m<2;m++)
    #pragma unroll
    for (int r=0;r<4;r++) accF[m][r] = fcb;
  #pragma unroll
  for (int kk=0;kk<2;kk++){
    #pragma unroll
    for (int m=0;m<2;m++){
      int row = m*16 + l15;
      int off = (row*128 + kk*64 + lg*16) ^ ((row&7)<<4);
      bf16x8 a = *(const bf16x8*)((const char*)h1s + off);
      accF[m] = __builtin_amdgcn_mfma_f32_16x16x32_bf16(a, wFC[kk], accF[m], 0,0,0);
    }
  }
  #pragma unroll
  for (int m=0;m<2;m++){
    #pragma unroll
    for (int r=0;r<4;r++){
      float v = accF[m][r];
      v = v > 0.f ? v : 0.f;
      out[(rbase + m*16 + lg*4 + r)*64 + w*16 + l15] = v;
    }
  }
}

extern "C" void kernel_launch(void* const* d_in, const int* in_sizes, int n_in,
                              void* d_out, int out_size, void* d_ws, size_t ws_size,
                              hipStream_t stream) {
  const float* x     = (const float*)d_in[0];
  const float* gamma = (const float*)d_in[1];
  const float* beta  = (const float*)d_in[2];
  const float* Wih0  = (const float*)d_in[3];
  const float* Whh0  = (const float*)d_in[4];
  const float* bih0  = (const float*)d_in[5];
  const float* bhh0  = (const float*)d_in[6];
  const float* Wih1  = (const float*)d_in[7];
  const float* Whh1  = (const float*)d_in[8];
  const float* bih1  = (const float*)d_in[9];
  const float* bhh1  = (const float*)d_in[10];
  const float* Wfc   = (const float*)d_in[11];
  const float* bfc   = (const float*)d_in[12];
  float* sums = (float*)d_ws;
  float* out  = (float*)d_out;

  hipMemsetAsync(d_ws, 0, 2*TSEQ*sizeof(float), stream);
  bn_stats<<<dim3(256), dim3(256), 0, stream>>>(x, sums);
  lstm_fused<<<dim3(BTOT/BM), dim3(256), 0, stream>>>(
      x, gamma, beta, Wih0, Whh0, bih0, bhh0,
      Wih1, Whh1, bih1, bhh1, Wfc, bfc, sums, out);
}